// Round 2
// baseline (686.006 us; speedup 1.0000x reference)
//
#include <hip/hip_runtime.h>

#define NN 128
#define ME 32
#define DI 64
#define NZ 96
#define ROWD 130
#define MAXIT 5000

// ---- LDS layout (double offsets). R: [0, 16640). Total 20040 dbl = 160320 B <= 163840.
#define OFF_UN 16640
#define ROWB  (OFF_UN)           // [2][128] sweep row-k buffer (phase 2)
#define COLB  (OFF_UN + 256)     // [2][128] sweep col-k buffer (phase 2)
// loop window: slot-major f32 partial exchange + split f64 obj pipeline
#define FPLO_F (2*(OFF_UN))        // FLOAT idx: [2][4][64] lo partials (slot-major)
#define FPHI_F (2*(OFF_UN) + 512)  // FLOAT idx: [2][4][32] hi partials (slot-major)
#define TV0L  (OFF_UN + 384)     // [2][64] obj lo terms (w0)
#define TV0H  (OFF_UN + 512)     // [2][32] obj hi terms (w3)
#define TV1   (OFF_UN + 576)     // [2][16] obj stage-A sums
#define FLG   (OFF_UN + 608)     // [2] convergence flag (double 0/1)
#define YBUF  (OFF_UN)           // [128][12] Y block (stage 2)
#define KBUF  (OFF_UN + 1536)    // [12][96] K cols (stage 2)
#define CPART (OFF_UN + 1024)    // [2][128] (stage 3a)
#define VP    (OFF_UN + 1280)    // [4][128] (stage 3b)
#define BASEV (OFF_UN + 1792)    // [96] (persists through loop)
#define QBV   (OFF_UN + 1888)    // [96] (persists through loop)
#define FPART (OFF_UN + 1024)    // [2][128] (final)
#define RHSV  (OFF_UN + 1280)    // [128] (final)
#define XPART (OFF_UN + 1408)    // [2][128] (final)
#define CB    (OFF_UN + 2688)    // [128] c
#define QBUF  (OFF_UN + 2816)    // [128] q
#define V1    (OFF_UN + 2944)    // [128] Rc
#define V2    (OFF_UN + 3072)    // [128] Rq
#define HB    (OFF_UN + 3200)    // [64]
#define BB    (OFF_UN + 3264)    // [32]
#define CST   (OFF_UN + 3296)    // [8]: 0=u.c 1=q.u
#define ZBF   (OFF_UN + 3304)    // [96] z publish (final)
#define LDS_DBL (OFF_UN + 3400)  // 20040

typedef __attribute__((ext_vector_type(2))) float f32x2;

// f32 SGPR broadcast. CONTRACT: source computed by all lanes of the wave.
__device__ __forceinline__ float rlf(float v, int lane) {
  return __uint_as_float((unsigned)__builtin_amdgcn_readlane((int)__float_as_uint(v), lane));
}
__device__ __forceinline__ f32x2 fma2(f32x2 a, f32x2 b, f32x2 c) {
  return __builtin_elementwise_fma(a, b, c);   // v_pk_fma_f32
}

// copy KBUF cols [KBASE, KBASE+CNT) into local K pairs starting at local col LBASE
#define CPYRANGE(LBASE, KBASE, CNT)                                        \
  _Pragma("unroll") for (int j = 0; j < (CNT); ++j) {                      \
    const int lj = (LBASE) + j, kc = (KBASE) + j;                          \
    float va = (float)ldsd[KBUF + kc*NZ + l];                              \
    float vb = (float)ldsd[KBUF + kc*NZ + 64 + lm];                        \
    if ((lj & 1) == 0) { Kp[lj>>1].x = va; Kp2[lj>>1].x = vb; }            \
    else               { Kp[lj>>1].y = va; Kp2[lj>>1].y = vb; }            \
  }

// matvec step: 2 pairs (4 cols) with broadcast lanes L0..L0+3 of ZS
#define MV2(PA, ZS, L0) {                                                  \
    f32x2 z0 = { rlf(ZS, L0), rlf(ZS, (L0)+1) };                           \
    A0 = fma2(Kp[PA], z0, A0); B0 = fma2(Kp2[PA], z0, B0);                 \
    f32x2 z1 = { rlf(ZS, (L0)+2), rlf(ZS, (L0)+3) };                       \
    A1 = fma2(Kp[(PA)+1], z1, A1); B1 = fma2(Kp2[(PA)+1], z1, B1); }
#define MV1(PA, ZS, L0) {                                                  \
    f32x2 z0 = { rlf(ZS, L0), rlf(ZS, (L0)+1) };                           \
    A0 = fma2(Kp[PA], z0, A0); B0 = fma2(Kp2[PA], z0, B0); }

__global__ __launch_bounds__(256, 1) void altdiff_kernel(
    const float* __restrict__ Qg, const float* __restrict__ qg,
    const float* __restrict__ Gg, const float* __restrict__ hg,
    const float* __restrict__ Ag, const float* __restrict__ bg,
    float* __restrict__ out)
{
  extern __shared__ double ldsd[];
  float* const ldsf = (float*)ldsd;

  const int bidx = blockIdx.x;
  const int tid  = threadIdx.x;
  const int w    = tid >> 6;     // wave 0..3
  const int l    = tid & 63;     // lane
  const int lm   = l & 31;
  const int ia   = tid & 127;    // 128-split index
  const int hh   = tid >> 7;     // 0..1 (wave-uniform)

  const float* Qb = Qg + (size_t)bidx * NN * NN;
  const float* Ab = Ag + (size_t)bidx * ME * NN;
  const float* Gb = Gg + (size_t)bidx * DI * NN;
  const float* qb = qg + (size_t)bidx * NN;
  const float* hb = hg + (size_t)bidx * DI;
  const float* bv = bg + (size_t)bidx * ME;

  // stage h, b, q (f64)
  if (tid < DI) ldsd[HB + tid] = (double)hb[tid];
  else if (tid < DI + ME) ldsd[BB + tid - DI] = (double)bv[tid - DI];
  if (tid >= 128) ldsd[QBUF + tid - 128] = (double)qb[tid - 128];

  const int r = tid >> 4, c = tid & 15;   // 8x8 register tile at rows 8r.., cols 8c..
  double acc[8][8];                       // ALL indices compile-time constant (no scratch)

  // ---------------- Phase 1: M = Q + A^T A + G^T G (f64) -> registers ----------------
  {
    const float4* Q4 = (const float4*)Qb;
#pragma unroll
    for (int rr = 0; rr < 8; ++rr) {
      float4 q0 = Q4[((8*r+rr) << 5) + 2*c];
      float4 q1 = Q4[((8*r+rr) << 5) + 2*c + 1];
      acc[rr][0]=(double)q0.x; acc[rr][1]=(double)q0.y; acc[rr][2]=(double)q0.z; acc[rr][3]=(double)q0.w;
      acc[rr][4]=(double)q1.x; acc[rr][5]=(double)q1.y; acc[rr][6]=(double)q1.z; acc[rr][7]=(double)q1.w;
    }
    const float4* A4 = (const float4*)Ab;
    for (int m = 0; m < ME; ++m) {
      float4 u0 = A4[(m << 5) + 2*r], u1 = A4[(m << 5) + 2*r + 1];
      float4 v0 = A4[(m << 5) + 2*c], v1 = A4[(m << 5) + 2*c + 1];
      double uu[8] = {(double)u0.x,(double)u0.y,(double)u0.z,(double)u0.w,
                      (double)u1.x,(double)u1.y,(double)u1.z,(double)u1.w};
      double vv[8] = {(double)v0.x,(double)v0.y,(double)v0.z,(double)v0.w,
                      (double)v1.x,(double)v1.y,(double)v1.z,(double)v1.w};
#pragma unroll
      for (int rr = 0; rr < 8; ++rr)
#pragma unroll
        for (int cc = 0; cc < 8; ++cc)
          acc[rr][cc] = fma(uu[rr], vv[cc], acc[rr][cc]);
    }
    const float4* G4 = (const float4*)Gb;
    for (int d = 0; d < DI; ++d) {
      float4 u0 = G4[(d << 5) + 2*r], u1 = G4[(d << 5) + 2*r + 1];
      float4 v0 = G4[(d << 5) + 2*c], v1 = G4[(d << 5) + 2*c + 1];
      double uu[8] = {(double)u0.x,(double)u0.y,(double)u0.z,(double)u0.w,
                      (double)u1.x,(double)u1.y,(double)u1.z,(double)u1.w};
      double vv[8] = {(double)v0.x,(double)v0.y,(double)v0.z,(double)v0.w,
                      (double)v1.x,(double)v1.y,(double)v1.z,(double)v1.w};
#pragma unroll
      for (int rr = 0; rr < 8; ++rr)
#pragma unroll
        for (int cc = 0; cc < 8; ++cc)
          acc[rr][cc] = fma(uu[rr], vv[cc], acc[rr][cc]);
    }
  }

  // ---------------- Phase 2: register-tile sweep, 1 barrier/pivot, double-buffered ----------
  {
    if (r == 0) {
#pragma unroll
      for (int cc = 0; cc < 8; ++cc) ldsd[ROWB + 8*c + cc] = acc[0][cc];
    }
    if (c == 0) {
#pragma unroll
      for (int rr = 0; rr < 8; ++rr) ldsd[COLB + 8*r + rr] = acc[rr][0];
    }
    __syncthreads();
    for (int k = 0; k < NN; ++k) {
      const int pb = (k & 1) << 7;
      const int krt = k >> 3, kcl = k & 7;
      double rowk[8], colv[8];
#pragma unroll
      for (int cc = 0; cc < 8; ++cc) rowk[cc] = ldsd[ROWB + pb + 8*c + cc];
#pragma unroll
      for (int rr = 0; rr < 8; ++rr) colv[rr] = ldsd[COLB + pb + 8*r + rr];
      const double dkk  = ldsd[ROWB + pb + k];     // same-address broadcast
      const double rcpd = 1.0 / dkk;               // pivots >= 1 (M >= I)
      double rdv[8];
#pragma unroll
      for (int cc = 0; cc < 8; ++cc) rdv[cc] = rowk[cc] * rcpd;
      const bool pivR = (r == krt), pivC = (c == krt);
#pragma unroll
      for (int rr = 0; rr < 8; ++rr) {
        const double cv = colv[rr] * rcpd;
        const bool pr = pivR && (rr == kcl);
#pragma unroll
        for (int cc = 0; cc < 8; ++cc) {
          double gen = fma(-cv, rowk[cc], acc[rr][cc]);
          acc[rr][cc] = pr ? rdv[cc] : gen;
        }
      }
      if (pivC) {
#pragma unroll
        for (int cc = 0; cc < 8; ++cc) if (cc == kcl) {
#pragma unroll
          for (int rr = 0; rr < 8; ++rr) {
            const bool pr2 = pivR && (rr == kcl);
            acc[rr][cc] = pr2 ? -rcpd : colv[rr] * rcpd;
          }
        }
      }
      if (k < NN - 1) {
        const int pb2 = ((k + 1) & 1) << 7;
        const int krt2 = (k + 1) >> 3, kcl2 = (k + 1) & 7;
        if (r == krt2) {
#pragma unroll
          for (int rr = 0; rr < 8; ++rr) if (rr == kcl2) {
#pragma unroll
            for (int cc = 0; cc < 8; ++cc) ldsd[ROWB + pb2 + 8*c + cc] = acc[rr][cc];
          }
        }
        if (c == krt2) {
#pragma unroll
          for (int cc = 0; cc < 8; ++cc) if (cc == kcl2) {
#pragma unroll
            for (int rr = 0; rr < 8; ++rr) ldsd[COLB + pb2 + 8*r + rr] = acc[rr][cc];
          }
        }
      }
      __syncthreads();
    }
#pragma unroll
    for (int rr = 0; rr < 8; ++rr) {
      double2* dst = (double2*)(ldsd + (8*r+rr)*ROWD + 8*c);
#pragma unroll
      for (int t = 0; t < 4; ++t) dst[t] = make_double2(acc[rr][2*t], acc[rr][2*t+1]);
    }
  }
  __syncthreads();

  // ---------------- Stage 2: K = B (R B^T) in 8 blocks of 12 cols --------
  // Column ownership (rebalanced by fixed duty): w0: 0..23, w1: 24..39, w2: 40..69, w3: 70..95.
  f32x2 Kp[15], Kp2[15];
  for (int blk = 0; blk < 8; ++blk) {
    {
      const float* gp[6];
#pragma unroll
      for (int jj = 0; jj < 6; ++jj) {
        int it = 12*blk + 6*hh + jj;
        gp[jj] = (it < DI) ? (Gb + it*NN) : (Ab + (it - DI)*NN);
      }
      double a2[6] = {0,0,0,0,0,0};
#pragma unroll 4
      for (int t = 0; t < NN; ++t) {
        double rv = ldsd[t*ROWD + ia];
#pragma unroll
        for (int jj = 0; jj < 6; ++jj)
          a2[jj] = fma(rv, (double)gp[jj][t], a2[jj]);
      }
      double2* yst = (double2*)(ldsd + YBUF + ia*12 + 6*hh);
#pragma unroll
      for (int p = 0; p < 3; ++p) yst[p] = make_double2(a2[2*p], a2[2*p+1]);
    }
    __syncthreads();
    {
      const int r2 = (ia < NZ) ? ia : 0;
      const float* brow = (r2 < DI) ? (Gb + r2*NN) : (Ab + (r2 - DI)*NN);
      double a2[6] = {0,0,0,0,0,0};
#pragma unroll 4
      for (int t = 0; t < NN; ++t) {
        double bvv = (double)brow[t];
        const double2* yr = (const double2*)(ldsd + YBUF + t*12 + 6*hh);
        double2 y0 = yr[0], y1 = yr[1], y2 = yr[2];
        a2[0] = fma(bvv, y0.x, a2[0]); a2[1] = fma(bvv, y0.y, a2[1]);
        a2[2] = fma(bvv, y1.x, a2[2]); a2[3] = fma(bvv, y1.y, a2[3]);
        a2[4] = fma(bvv, y2.x, a2[4]); a2[5] = fma(bvv, y2.y, a2[5]);
      }
      if (ia < NZ) {
#pragma unroll
        for (int jj = 0; jj < 6; ++jj) ldsd[KBUF + (6*hh + jj)*NZ + ia] = a2[jj];
      }
    }
    __syncthreads();
    // copy-out: constant indices per (wave, blk) arm
    if (w == 0) {
      if (blk == 0)      { CPYRANGE(0,  0, 12) }
      else if (blk == 1) { CPYRANGE(12, 0, 12) }
    } else if (w == 1) {
      if (blk == 2)      { CPYRANGE(0,  0, 12) }
      else if (blk == 3) { CPYRANGE(12, 0, 4) }
    } else if (w == 2) {
      if (blk == 3)      { CPYRANGE(0,  4, 8) }
      else if (blk == 4) { CPYRANGE(8,  0, 12) }
      else if (blk == 5) { CPYRANGE(20, 0, 10) }
    } else {
      if (blk == 5)      { CPYRANGE(0,  10, 2) }
      else if (blk == 6) { CPYRANGE(2,  0, 12) }
      else if (blk == 7) { CPYRANGE(14, 0, 12) }
    }
    __syncthreads();
  }

  // ---------------- Stage 3a: c = q - G^T h - A^T b ----------------
  {
    double s = 0;
#pragma unroll 8
    for (int jc = 0; jc < 48; ++jc) {
      int j = 48*hh + jc;
      double coef = (j < DI) ? ldsd[HB + j] : ldsd[BB + j - DI];
      const float* src = (j < DI) ? (Gb + j*NN) : (Ab + (j - DI)*NN);
      s = fma(-(double)src[ia], coef, s);
    }
    ldsd[CPART + hh*128 + ia] = s;
  }
  __syncthreads();
  if (tid < NN) ldsd[CB + tid] = ldsd[QBUF + tid] + ldsd[CPART + tid] + ldsd[CPART + 128 + tid];
  __syncthreads();

  // ---------------- Stage 3b: v1 = R c, v2 = R q ----------------
  {
    double a = 0, b2 = 0;
#pragma unroll 4
    for (int tt = 0; tt < 64; ++tt) {
      int t = 64*hh + tt;
      double rv = ldsd[t*ROWD + ia];
      a  = fma(rv, ldsd[CB + t], a);
      b2 = fma(rv, ldsd[QBUF + t], b2);
    }
    ldsd[VP + hh*128 + ia] = a;
    ldsd[VP + 256 + hh*128 + ia] = b2;
  }
  __syncthreads();
  if (tid < NN) {
    ldsd[V1 + tid] = ldsd[VP + tid] + ldsd[VP + 128 + tid];
    ldsd[V2 + tid] = ldsd[VP + 256 + tid] + ldsd[VP + 384 + tid];
  }
  __syncthreads();

  // ---------------- Stage 3c: base = B v1, qB = B v2, scalars ----------------
  {
    const int r2 = (ia < NZ) ? ia : 0;
    const float* brow = (r2 < DI) ? (Gb + r2*NN) : (Ab + (r2 - DI)*NN);
    const int voff = hh ? V2 : V1;
    double s = 0;
#pragma unroll 4
    for (int t = 0; t < NN; ++t) s = fma((double)brow[t], ldsd[voff + t], s);
    if (ia < NZ) ldsd[(hh ? QBV : BASEV) + ia] = s;
  }
  if (w == 0) {
    double pc = ldsd[V1+l]*ldsd[CB+l]   + ldsd[V1+64+l]*ldsd[CB+64+l];
    double pq = ldsd[V1+l]*ldsd[QBUF+l] + ldsd[V1+64+l]*ldsd[QBUF+64+l];
#pragma unroll
    for (int off = 32; off >= 1; off >>= 1) { pc += __shfl_xor(pc, off); pq += __shfl_xor(pq, off); }
    if (l == 0) { ldsd[CST] = pc; ldsd[CST+1] = pq; }
  }
  __syncthreads();

  // ---------------- Loop setup: duty-balanced roles ----------------
  // w0: 24 lo cols + lo-ring + tv-lo     | w1: 16 lo cols + stage B + flag
  // w2: 24 lo + 6 hi cols (no ring/tv)   | w3: 26 hi cols + hi-ring + tv-hi + stage A
  // Shortened chain: z_lo = |t|, t = hnb - slo, hnb = (h - baseA) - nu (off-path);
  //                  z_hi = lam' = lb + shi, lb = lam' + (baseB - b) (off-path).
  const double baseA = ldsd[BASEV + l];
  const double baseB = ldsd[BASEV + 64 + lm];
  const double qvA   = ldsd[QBV + l];
  const double qvB   = ldsd[QBV + 64 + lm];
  const double hb2   = ldsd[HB + l] - baseA;       // h - baseA
  const double bb2   = baseB - ldsd[BB + lm];      // baseB - b
  const double S_uc  = ldsd[CST], S_qu = ldsd[CST + 1];
  double hnb = hb2, lb = bb2;                      // nu = 0, lam = 0
  double zlo = 0.0, zhi = 0.0;
  double zAlo = 0.0, zAhi = 0.0, zBlo = 0.0, zBhi = 0.0, zClo = 0.0, zChi = 0.0;
  double res_prev = 1000.0, res_cur = -100.0;      // wave-1 obj recurrence

  // prologue: zero partials buffer 0 (base folded into hb2/bb2); flag init
  {
    ldsf[FPLO_F + (w << 6) + l] = 0.f;
    if (l < 32) ldsf[FPHI_F + (w << 5) + l] = 0.f;
    if (tid == 0) { ldsd[FLG] = 0.0; ldsd[FLG + 1] = 0.0; }
  }

  // ---------------- ADMM loop: 1 barrier/body ----------------
  for (int it = 0; it < MAXIT + 3; ++it) {
    __syncthreads();
    const int buf = it & 1, nbuf = buf ^ 1;
    const int bprev = (it + 1) & 1;       // (it-1)&1
    double fl = ldsd[FLG + bprev];
    // partial reads — slot-major: 4 stride-64 b32 (conflict-free, read2-pairable)
    float p0 = 0.f, p1 = 0.f, p2 = 0.f, p3 = 0.f, q0 = 0.f, q1 = 0.f, q2 = 0.f, q3 = 0.f;
    if (w != 3) {
      const int fb = FPLO_F + (buf << 8) + l;
      p0 = ldsf[fb]; p1 = ldsf[fb + 64]; p2 = ldsf[fb + 128]; p3 = ldsf[fb + 192];
    }
    if (w >= 2) {
      const int fb = FPHI_F + (buf << 7) + lm;
      q0 = ldsf[fb]; q1 = ldsf[fb + 32]; q2 = ldsf[fb + 64]; q3 = ldsf[fb + 96];
    }
    // stage B loads (w1, pipeline it-2): wave-uniform broadcast
    double t1v[16];
    if (w == 1) {
      const double2* tp = (const double2*)(ldsd + TV1 + bprev*16);
#pragma unroll
      for (int u = 0; u < 8; ++u) { double2 v = tp[u]; t1v[2*u] = v.x; t1v[2*u+1] = v.y; }
    }
    // stage A loads (w3, pipeline it-1): stride-16 quartets, conflict-free
    double a40 = 0, a41 = 0, a42 = 0, a43 = 0, a44 = 0, a45 = 0;
    if (w == 3) {
      const int g = l & 15;
      const double* tl = ldsd + TV0L + bprev*64;
      const double* th = ldsd + TV0H + bprev*32;
      a40 = tl[g]; a41 = tl[g + 16]; a42 = tl[g + 32]; a43 = tl[g + 48];
      a44 = th[g]; a45 = th[g + 16];
    }
    // chains (short): lo = 4 ops to zflo; hi = 3 ops to zfhi
    double slo = 0.0, t = 0.0, shi = 0.0, lamn = 0.0;
    float zflo = 0.f, zfhi = 0.f;
    if (w != 3) {
      float s = (p0 + p1) + (p2 + p3);
      slo = (double)s; t = hnb - slo;
      zflo = (float)fabs(t);
    }
    if (w >= 2) {
      float sh = (q0 + q1) + (q2 + q3);
      shi = (double)sh; lamn = lb + shi;
      zfhi = (float)lamn;
    }
    // uniform deferred break BEFORE ring shift: ring = top(it-2) in zC
    if (it >= 3 && fl != 0.0) break;
    // ring shifts (zA = z entering THIS body)
    if (w == 0) { zClo = zBlo; zBlo = zAlo; zAlo = zlo; }
    if (w == 3) { zChi = zBhi; zBhi = zAhi; zAhi = zhi; }
    if (it < MAXIT) {
      // off-path state updates
      if (w == 0) zlo = fabs(t);
      if (w != 3) hnb = hb2 + fmin(t, 0.0);          // = hb2 - relu(-t)
      if (w == 3) zhi = lamn;
      if (w >= 2) lb = lamn + bb2;
      // matvec burst (duty-balanced column counts)
      f32x2 A0 = {0.f, 0.f}, A1 = A0, B0 = A0, B1 = A0;
      if (w == 0) {
        MV2(0, zflo, 0)  MV2(2, zflo, 4)  MV2(4, zflo, 8)
        MV2(6, zflo, 12) MV2(8, zflo, 16) MV2(10, zflo, 20)
      } else if (w == 1) {
        MV2(0, zflo, 24) MV2(2, zflo, 28) MV2(4, zflo, 32) MV2(6, zflo, 36)
      } else if (w == 2) {
        MV2(0, zflo, 40) MV2(2, zflo, 44) MV2(4, zflo, 48)
        MV2(6, zflo, 52) MV2(8, zflo, 56) MV2(10, zflo, 60)
        MV2(12, zfhi, 0) MV1(14, zfhi, 4)
      } else {
        MV2(0, zfhi, 6)  MV2(2, zfhi, 10) MV2(4, zfhi, 14)
        MV2(6, zfhi, 18) MV2(8, zfhi, 22) MV2(10, zfhi, 26)
        MV1(12, zfhi, 30)
      }
      f32x2 As = A0 + A1, Bs = B0 + B1;     // v_pk_add_f32
      float pa0 = As.x + As.y;
      float pa1 = Bs.x + Bs.y;
      // slot-major stores: lane-consecutive -> conflict-free
      ldsf[FPLO_F + (nbuf << 8) + (w << 6) + l] = pa0;
      if (l < 32) ldsf[FPHI_F + (nbuf << 7) + (w << 5) + l] = pa1;
      // tv terms (split): lo on w0, hi on w3 — off the w2 path
      if (w == 0) {
        double yfull = slo + baseA;
        double tvl = fma(qvA, zAlo, -0.5*(zAlo*(baseA + yfull) + yfull*yfull));
        ldsd[TV0L + buf*64 + l] = tvl;
      }
      if (w == 3) {
        double yfB = shi + baseB;
        double tvh = fma(qvB, zAhi, -0.5*(zAhi*(baseB + yfB) + yfB*yfB));
        if (l < 32) ldsd[TV0H + buf*32 + l] = tvh;
      }
    }
    // stage A store (w3, pipeline it-1)
    if (w == 3 && l < 16 && it >= 1 && it <= MAXIT)
      ldsd[TV1 + buf*16 + l] = ((a40 + a41) + (a42 + a43)) + (a44 + a45);
    // stage B (w1): obj_{it-2} -> rel -> flag (division-free predicate)
    if (w == 1 && it >= 2 && it <= MAXIT + 1) {
      double s1 = ((t1v[0] + t1v[1]) + (t1v[2] + t1v[3])) + ((t1v[4] + t1v[5]) + (t1v[6] + t1v[7]));
      double s2 = ((t1v[8] + t1v[9]) + (t1v[10] + t1v[11])) + ((t1v[12] + t1v[13]) + (t1v[14] + t1v[15]));
      double obj = (s1 + s2) - 0.5*S_uc + S_qu;
      res_prev = res_cur; res_cur = obj;
      if (l == 0)
        ldsd[FLG + buf] = (fabs(res_cur - res_prev) <= 1e-5 * fabs(res_prev)) ? 1.0 : 0.0;
    }
  }

  // ---------------- Final: publish z (rings: zC = top-of-stopping-body) -> LDS ------
  if (w == 0) ldsd[ZBF + l] = zClo;
  if (w == 3 && l < 32) ldsd[ZBF + 64 + l] = zChi;
  __syncthreads();
  // x = R (c + B^T z); z read via broadcast LDS loads
  {
    double s = 0;
#pragma unroll 8
    for (int jc = 0; jc < 48; ++jc) {
      int j = 48*hh + jc;
      double zj = ldsd[ZBF + j];
      const float* src = (j < DI) ? (Gb + j*NN) : (Ab + (j - DI)*NN);
      s = fma((double)src[ia], zj, s);
    }
    ldsd[FPART + hh*128 + ia] = s;
  }
  __syncthreads();
  if (tid < NN) ldsd[RHSV + tid] = ldsd[CB + tid] + ldsd[FPART + tid] + ldsd[FPART + 128 + tid];
  __syncthreads();
  {
    double s = 0;
#pragma unroll 4
    for (int tt = 0; tt < 64; ++tt) {
      int t = 64*hh + tt;
      s = fma(ldsd[t*ROWD + ia], ldsd[RHSV + t], s);   // R[t][ia] = R[ia][t]
    }
    ldsd[XPART + hh*128 + ia] = s;
  }
  __syncthreads();
  if (tid < NN)
    out[(size_t)bidx * NN + tid] = (float)(ldsd[XPART + tid] + ldsd[XPART + 128 + tid]);
}

extern "C" void kernel_launch(void* const* d_in, const int* in_sizes, int n_in,
                              void* d_out, int out_size, void* d_ws, size_t ws_size,
                              hipStream_t stream) {
  (void)in_sizes; (void)n_in; (void)out_size; (void)d_ws; (void)ws_size;
  const float* Q = (const float*)d_in[0];
  const float* q = (const float*)d_in[1];
  const float* G = (const float*)d_in[2];
  const float* h = (const float*)d_in[3];
  const float* A = (const float*)d_in[4];
  const float* b = (const float*)d_in[5];
  float* out = (float*)d_out;
  const size_t lds_bytes = (size_t)LDS_DBL * sizeof(double);  // 160320
  altdiff_kernel<<<dim3(64), dim3(256), lds_bytes, stream>>>(Q, q, G, h, A, b, out);
}